// Round 7
// baseline (888.047 us; speedup 1.0000x reference)
//
#include <hip/hip_runtime.h>
#include <hip/hip_cooperative_groups.h>
#include <math.h>

namespace cg = cooperative_groups;

#define NEG_INF (-INFINITY)

typedef int      v4i __attribute__((ext_vector_type(4)));
typedef float    v4f __attribute__((ext_vector_type(4)));
typedef _Float16 v4h __attribute__((ext_vector_type(4)));

// fast log1mexp for v < 0: log(1 - e^v). Rel err ~1e-6.
__device__ __forceinline__ float fast_log1mexp(float v) {
    if (v > -0.125f) {
        float e = v * (1.0f + v * (0.5f + v * (0.16666667f + v * 0.041666667f)));
        return __logf(-e);
    }
    return __logf(1.0f - __expf(v));
}

// encoded-x ptr -> clamped index into wh
__device__ __forceinline__ int widx(int p) { int j = (p >> 1) - 1; return j < 0 ? 0 : j; }
// fixup a raw gathered weight per ptr parity/constants
__device__ __forceinline__ float fixw(int p, float v) {
    float r = (p & 1) ? fast_log1mexp(v) : v;
    if (p < 2) r = (p == 0) ? NEG_INF : 0.0f;
    return r;
}

__device__ __forceinline__ float lse4(float a, float b, float c, float d) {
    float m = fmaxf(fmaxf(a, b), fmaxf(c, d));
    if (m == NEG_INF) return NEG_INF;       // all four -inf: ref yields -inf
    float s = __expf(a - m) + __expf(b - m) + __expf(c - m) + __expf(d - m) + 1e-15f;
    return __logf(s) + m;
}

// One persistent cooperative kernel: cvt | enc+prod | lse | prod | lse,
// separated by grid-wide syncs. Straight-line 4-node bodies (16 gathers in
// flight per thread) — round-6 shape, now at 32 waves/CU.
__global__ void __launch_bounds__(256, 8)
fused_kernel(const float* __restrict__ w,
             const v4i* __restrict__ ptrs0, const v4i* __restrict__ ptrs1,
             const v4i* __restrict__ ptrs2, const v4i* __restrict__ ptrs3,
             _Float16* __restrict__ wh, _Float16* __restrict__ y0,
             _Float16* __restrict__ y1, _Float16* __restrict__ y2,
             float* __restrict__ out,
             int n_vars, int n0, int n1, int n2, int n3) {
    cg::grid_group grid = cg::this_grid();
    const int T = gridDim.x * blockDim.x;
    const int t = blockIdx.x * blockDim.x + threadIdx.x;

    // ---- stage 0: w (fp32) -> wh (fp16), vectorized ----
    int n4 = n_vars >> 2;
    for (int i = t; i < n4; i += T) {
        v4f v = reinterpret_cast<const v4f*>(w)[i];
        v4h o;
        o.x = (_Float16)v.x; o.y = (_Float16)v.y;
        o.z = (_Float16)v.z; o.w = (_Float16)v.w;
        reinterpret_cast<v4h*>(wh)[i] = o;
    }
    for (int i = (n4 << 2) + t; i < n_vars; i += T) wh[i] = (_Float16)w[i];
    grid.sync();

    // ---- stage 1: product node fused with encode -> y0 ----
    for (int base = t; base < n0; base += 4 * T) {
        int i0 = base, i1 = base + T, i2 = base + 2 * T, i3 = base + 3 * T;
        int c1 = i1 < n0 ? i1 : 0, c2 = i2 < n0 ? i2 : 0, c3 = i3 < n0 ? i3 : 0;
        v4i p0 = __builtin_nontemporal_load(ptrs0 + i0);
        v4i p1 = __builtin_nontemporal_load(ptrs0 + c1);
        v4i p2 = __builtin_nontemporal_load(ptrs0 + c2);
        v4i p3 = __builtin_nontemporal_load(ptrs0 + c3);
        float g00 = (float)wh[widx(p0.x)], g01 = (float)wh[widx(p0.y)];
        float g02 = (float)wh[widx(p0.z)], g03 = (float)wh[widx(p0.w)];
        float g10 = (float)wh[widx(p1.x)], g11 = (float)wh[widx(p1.y)];
        float g12 = (float)wh[widx(p1.z)], g13 = (float)wh[widx(p1.w)];
        float g20 = (float)wh[widx(p2.x)], g21 = (float)wh[widx(p2.y)];
        float g22 = (float)wh[widx(p2.z)], g23 = (float)wh[widx(p2.w)];
        float g30 = (float)wh[widx(p3.x)], g31 = (float)wh[widx(p3.y)];
        float g32 = (float)wh[widx(p3.z)], g33 = (float)wh[widx(p3.w)];
        float s0 = (fixw(p0.x, g00) + fixw(p0.y, g01)) + (fixw(p0.z, g02) + fixw(p0.w, g03));
        float s1 = (fixw(p1.x, g10) + fixw(p1.y, g11)) + (fixw(p1.z, g12) + fixw(p1.w, g13));
        float s2 = (fixw(p2.x, g20) + fixw(p2.y, g21)) + (fixw(p2.z, g22) + fixw(p2.w, g23));
        float s3 = (fixw(p3.x, g30) + fixw(p3.y, g31)) + (fixw(p3.z, g32) + fixw(p3.w, g33));
        y0[i0] = (_Float16)s0;
        if (i1 < n0) y0[i1] = (_Float16)s1;
        if (i2 < n0) y0[i2] = (_Float16)s2;
        if (i3 < n0) y0[i3] = (_Float16)s3;
    }
    grid.sync();

    // ---- stage 2: sum node (LSE) y0 -> y1 ----
    for (int base = t; base < n1; base += 4 * T) {
        int i0 = base, i1 = base + T, i2 = base + 2 * T, i3 = base + 3 * T;
        int c1 = i1 < n1 ? i1 : 0, c2 = i2 < n1 ? i2 : 0, c3 = i3 < n1 ? i3 : 0;
        v4i p0 = __builtin_nontemporal_load(ptrs1 + i0);
        v4i p1 = __builtin_nontemporal_load(ptrs1 + c1);
        v4i p2 = __builtin_nontemporal_load(ptrs1 + c2);
        v4i p3 = __builtin_nontemporal_load(ptrs1 + c3);
        float a0 = (float)y0[p0.x], b0 = (float)y0[p0.y], e0 = (float)y0[p0.z], d0 = (float)y0[p0.w];
        float a1 = (float)y0[p1.x], b1 = (float)y0[p1.y], e1 = (float)y0[p1.z], d1 = (float)y0[p1.w];
        float a2 = (float)y0[p2.x], b2 = (float)y0[p2.y], e2 = (float)y0[p2.z], d2 = (float)y0[p2.w];
        float a3 = (float)y0[p3.x], b3 = (float)y0[p3.y], e3 = (float)y0[p3.z], d3 = (float)y0[p3.w];
        float s0 = lse4(a0, b0, e0, d0);
        float s1 = lse4(a1, b1, e1, d1);
        float s2 = lse4(a2, b2, e2, d2);
        float s3 = lse4(a3, b3, e3, d3);
        y1[i0] = (_Float16)s0;
        if (i1 < n1) y1[i1] = (_Float16)s1;
        if (i2 < n1) y1[i2] = (_Float16)s2;
        if (i3 < n1) y1[i3] = (_Float16)s3;
    }
    grid.sync();

    // ---- stage 3: product node y1 -> y2 ----
    for (int base = t; base < n2; base += 4 * T) {
        int i0 = base, i1 = base + T, i2 = base + 2 * T, i3 = base + 3 * T;
        int c0 = i0 < n2 ? i0 : 0;
        int c1 = i1 < n2 ? i1 : 0, c2 = i2 < n2 ? i2 : 0, c3 = i3 < n2 ? i3 : 0;
        v4i p0 = __builtin_nontemporal_load(ptrs2 + c0);
        v4i p1 = __builtin_nontemporal_load(ptrs2 + c1);
        v4i p2 = __builtin_nontemporal_load(ptrs2 + c2);
        v4i p3 = __builtin_nontemporal_load(ptrs2 + c3);
        float s0 = ((float)y1[p0.x] + (float)y1[p0.y]) + ((float)y1[p0.z] + (float)y1[p0.w]);
        float s1 = ((float)y1[p1.x] + (float)y1[p1.y]) + ((float)y1[p1.z] + (float)y1[p1.w]);
        float s2 = ((float)y1[p2.x] + (float)y1[p2.y]) + ((float)y1[p2.z] + (float)y1[p2.w]);
        float s3 = ((float)y1[p3.x] + (float)y1[p3.y]) + ((float)y1[p3.z] + (float)y1[p3.w]);
        if (i0 < n2) y2[i0] = (_Float16)s0;
        if (i1 < n2) y2[i1] = (_Float16)s1;
        if (i2 < n2) y2[i2] = (_Float16)s2;
        if (i3 < n2) y2[i3] = (_Float16)s3;
    }
    grid.sync();

    // ---- stage 4: sum node (LSE) y2 -> out (fp32) ----
    for (int base = t; base < n3; base += 4 * T) {
        int i0 = base, i1 = base + T, i2 = base + 2 * T, i3 = base + 3 * T;
        int c0 = i0 < n3 ? i0 : 0;
        int c1 = i1 < n3 ? i1 : 0, c2 = i2 < n3 ? i2 : 0, c3 = i3 < n3 ? i3 : 0;
        v4i p0 = __builtin_nontemporal_load(ptrs3 + c0);
        v4i p1 = __builtin_nontemporal_load(ptrs3 + c1);
        v4i p2 = __builtin_nontemporal_load(ptrs3 + c2);
        v4i p3 = __builtin_nontemporal_load(ptrs3 + c3);
        float a0 = (float)y2[p0.x], b0 = (float)y2[p0.y], e0 = (float)y2[p0.z], d0 = (float)y2[p0.w];
        float a1 = (float)y2[p1.x], b1 = (float)y2[p1.y], e1 = (float)y2[p1.z], d1 = (float)y2[p1.w];
        float a2 = (float)y2[p2.x], b2 = (float)y2[p2.y], e2 = (float)y2[p2.z], d2 = (float)y2[p2.w];
        float a3 = (float)y2[p3.x], b3 = (float)y2[p3.y], e3 = (float)y2[p3.z], d3 = (float)y2[p3.w];
        float s0 = lse4(a0, b0, e0, d0);
        float s1 = lse4(a1, b1, e1, d1);
        float s2 = lse4(a2, b2, e2, d2);
        float s3 = lse4(a3, b3, e3, d3);
        if (i0 < n3) __builtin_nontemporal_store(s0, out + i0);
        if (i1 < n3) __builtin_nontemporal_store(s1, out + i1);
        if (i2 < n3) __builtin_nontemporal_store(s2, out + i2);
        if (i3 < n3) __builtin_nontemporal_store(s3, out + i3);
    }
}

extern "C" void kernel_launch(void* const* d_in, const int* in_sizes, int n_in,
                              void* d_out, int out_size, void* d_ws, size_t ws_size,
                              hipStream_t stream) {
    // d_in dict order: weights, ptrs0, csr0, n0, ptrs1, csr1, n1, ptrs2, csr2, n2, ptrs3, csr3, n3
    const float* w     = (const float*)d_in[0];
    const v4i*   ptrs0 = (const v4i*)d_in[1];
    const v4i*   ptrs1 = (const v4i*)d_in[4];
    const v4i*   ptrs2 = (const v4i*)d_in[7];
    const v4i*   ptrs3 = (const v4i*)d_in[10];

    int n_vars = in_sizes[0];
    int n0 = in_sizes[1] / 4;
    int n1 = in_sizes[4] / 4;
    int n2 = in_sizes[7] / 4;
    int n3 = in_sizes[10] / 4;

    // workspace layout (256B-aligned), intermediates fp16
    char* ws = (char*)d_ws;
    size_t off = 0;
    _Float16* wh = (_Float16*)(ws + off); off += ((size_t)n_vars * 2 + 255) & ~(size_t)255;
    _Float16* y0 = (_Float16*)(ws + off); off += ((size_t)n0 * 2 + 255) & ~(size_t)255;
    _Float16* y1 = (_Float16*)(ws + off); off += ((size_t)n1 * 2 + 255) & ~(size_t)255;
    _Float16* y2 = (_Float16*)(ws + off);
    float* out = (float*)d_out;

    // co-resident grid: blocks/CU from occupancy query × CU count
    hipDeviceProp_t prop;
    hipGetDeviceProperties(&prop, 0);
    int bpcu = 0;
    hipOccupancyMaxActiveBlocksPerMultiprocessor(&bpcu, (const void*)fused_kernel, 256, 0);
    if (bpcu < 1) bpcu = 1;
    int grid = prop.multiProcessorCount * bpcu;
    if (grid > 2048) grid = 2048;

    void* args[] = { (void*)&w, (void*)&ptrs0, (void*)&ptrs1, (void*)&ptrs2, (void*)&ptrs3,
                     (void*)&wh, (void*)&y0, (void*)&y1, (void*)&y2, (void*)&out,
                     (void*)&n_vars, (void*)&n0, (void*)&n1, (void*)&n2, (void*)&n3 };
    hipLaunchCooperativeKernel((const void*)fused_kernel, dim3(grid), dim3(256), args, 0, stream);
}

// Round 8
// 357.015 us; speedup vs baseline: 2.4874x; 2.4874x over previous
//
#include <hip/hip_runtime.h>
#include <math.h>

#define NEG_INF (-INFINITY)

typedef int      v4i __attribute__((ext_vector_type(4)));
typedef float    v4f __attribute__((ext_vector_type(4)));
typedef _Float16 v4h __attribute__((ext_vector_type(4)));

// fast log1mexp for v < 0: log(1 - e^v). Rel err ~1e-6.
__device__ __forceinline__ float fast_log1mexp(float v) {
    if (v > -0.125f) {
        float e = v * (1.0f + v * (0.5f + v * (0.16666667f + v * 0.041666667f)));
        return __logf(-e);
    }
    return __logf(1.0f - __expf(v));
}

// w (fp32) -> wh (fp16)
__global__ __launch_bounds__(256) void cvt_kernel(const float* __restrict__ w,
                                                  _Float16* __restrict__ wh, int n) {
    int i = blockIdx.x * blockDim.x + threadIdx.x;
    int n4 = n >> 2;
    if (i < n4) {
        v4f v = reinterpret_cast<const v4f*>(w)[i];
        v4h o;
        o.x = (_Float16)v.x; o.y = (_Float16)v.y;
        o.z = (_Float16)v.z; o.w = (_Float16)v.w;
        reinterpret_cast<v4h*>(wh)[i] = o;
    }
    int base = n4 << 2;
    if (i < (n - base)) wh[base + i] = (_Float16)w[base + i];
}

// encoded-x ptr -> clamped index into wh
__device__ __forceinline__ int widx(int p) { int j = (p >> 1) - 1; return j < 0 ? 0 : j; }
// fixup a raw gathered weight per ptr parity/constants
__device__ __forceinline__ float fixw(int p, float v) {
    float r = (p & 1) ? fast_log1mexp(v) : v;
    if (p < 2) r = (p == 0) ? NEG_INF : 0.0f;
    return r;
}

// Layer 0: product node fused with encode. 4 nodes/thread, straight-line.
__global__ __launch_bounds__(256) void sum4_enc_kernel(const _Float16* __restrict__ wh,
                                                       const v4i* __restrict__ ptrs,
                                                       _Float16* __restrict__ y, int n, int h) {
    int t = blockIdx.x * blockDim.x + threadIdx.x;
    if (t >= h) return;
    int i0 = t, i1 = t + h, i2 = t + 2 * h, i3 = t + 3 * h;
    int c1 = i1 < n ? i1 : 0, c2 = i2 < n ? i2 : 0, c3 = i3 < n ? i3 : 0;
    v4i p0 = __builtin_nontemporal_load(ptrs + i0);
    v4i p1 = __builtin_nontemporal_load(ptrs + c1);
    v4i p2 = __builtin_nontemporal_load(ptrs + c2);
    v4i p3 = __builtin_nontemporal_load(ptrs + c3);
    float g00 = (float)wh[widx(p0.x)], g01 = (float)wh[widx(p0.y)];
    float g02 = (float)wh[widx(p0.z)], g03 = (float)wh[widx(p0.w)];
    float g10 = (float)wh[widx(p1.x)], g11 = (float)wh[widx(p1.y)];
    float g12 = (float)wh[widx(p1.z)], g13 = (float)wh[widx(p1.w)];
    float g20 = (float)wh[widx(p2.x)], g21 = (float)wh[widx(p2.y)];
    float g22 = (float)wh[widx(p2.z)], g23 = (float)wh[widx(p2.w)];
    float g30 = (float)wh[widx(p3.x)], g31 = (float)wh[widx(p3.y)];
    float g32 = (float)wh[widx(p3.z)], g33 = (float)wh[widx(p3.w)];
    float s0 = (fixw(p0.x, g00) + fixw(p0.y, g01)) + (fixw(p0.z, g02) + fixw(p0.w, g03));
    float s1 = (fixw(p1.x, g10) + fixw(p1.y, g11)) + (fixw(p1.z, g12) + fixw(p1.w, g13));
    float s2 = (fixw(p2.x, g20) + fixw(p2.y, g21)) + (fixw(p2.z, g22) + fixw(p2.w, g23));
    float s3 = (fixw(p3.x, g30) + fixw(p3.y, g31)) + (fixw(p3.z, g32) + fixw(p3.w, g33));
    __builtin_nontemporal_store((_Float16)s0, y + i0);
    if (i1 < n) __builtin_nontemporal_store((_Float16)s1, y + i1);
    if (i2 < n) __builtin_nontemporal_store((_Float16)s2, y + i2);
    if (i3 < n) __builtin_nontemporal_store((_Float16)s3, y + i3);
}

// partial stable LSE over one node's in-partition gathers (no epsilon):
// returns -inf if no in-partition finite values.
__device__ __forceinline__ float plse4(float a, float b, float c, float d) {
    float m = fmaxf(fmaxf(a, b), fmaxf(c, d));
    if (m == NEG_INF) return NEG_INF;
    float s = __expf(a - m) + __expf(b - m) + __expf(c - m) + __expf(d - m);
    return __logf(s) + m;
}

// Layer 1 pass A: predicated gathers from the L2-resident lower half of y0;
// emit per-node partial LSE (fp16).
__global__ __launch_bounds__(256) void l1a_kernel(const _Float16* __restrict__ x,
                                                  const v4i* __restrict__ ptrs,
                                                  _Float16* __restrict__ LA,
                                                  int n, int h, int half) {
    int t = blockIdx.x * blockDim.x + threadIdx.x;
    if (t >= h) return;
    int i0 = t, i1 = t + h, i2 = t + 2 * h, i3 = t + 3 * h;
    int c1 = i1 < n ? i1 : 0, c2 = i2 < n ? i2 : 0, c3 = i3 < n ? i3 : 0;
    v4i p0 = __builtin_nontemporal_load(ptrs + i0);
    v4i p1 = __builtin_nontemporal_load(ptrs + c1);
    v4i p2 = __builtin_nontemporal_load(ptrs + c2);
    v4i p3 = __builtin_nontemporal_load(ptrs + c3);
    float a0 = NEG_INF, b0 = NEG_INF, e0 = NEG_INF, d0 = NEG_INF;
    float a1 = NEG_INF, b1 = NEG_INF, e1 = NEG_INF, d1 = NEG_INF;
    float a2 = NEG_INF, b2 = NEG_INF, e2 = NEG_INF, d2 = NEG_INF;
    float a3 = NEG_INF, b3 = NEG_INF, e3 = NEG_INF, d3 = NEG_INF;
    if (p0.x < half) a0 = (float)x[p0.x];
    if (p0.y < half) b0 = (float)x[p0.y];
    if (p0.z < half) e0 = (float)x[p0.z];
    if (p0.w < half) d0 = (float)x[p0.w];
    if (p1.x < half) a1 = (float)x[p1.x];
    if (p1.y < half) b1 = (float)x[p1.y];
    if (p1.z < half) e1 = (float)x[p1.z];
    if (p1.w < half) d1 = (float)x[p1.w];
    if (p2.x < half) a2 = (float)x[p2.x];
    if (p2.y < half) b2 = (float)x[p2.y];
    if (p2.z < half) e2 = (float)x[p2.z];
    if (p2.w < half) d2 = (float)x[p2.w];
    if (p3.x < half) a3 = (float)x[p3.x];
    if (p3.y < half) b3 = (float)x[p3.y];
    if (p3.z < half) e3 = (float)x[p3.z];
    if (p3.w < half) d3 = (float)x[p3.w];
    float s0 = plse4(a0, b0, e0, d0);
    float s1 = plse4(a1, b1, e1, d1);
    float s2 = plse4(a2, b2, e2, d2);
    float s3 = plse4(a3, b3, e3, d3);
    __builtin_nontemporal_store((_Float16)s0, LA + i0);
    if (i1 < n) __builtin_nontemporal_store((_Float16)s1, LA + i1);
    if (i2 < n) __builtin_nontemporal_store((_Float16)s2, LA + i2);
    if (i3 < n) __builtin_nontemporal_store((_Float16)s3, LA + i3);
}

// Layer 1 pass B: predicated gathers from the upper half; exact merge with LA.
__device__ __forceinline__ float merge_lse(float LA, float LB) {
    float m = fmaxf(LA, LB);
    if (m == NEG_INF) return NEG_INF;
    float s = __expf(LA - m) + __expf(LB - m) + 1e-15f;
    return __logf(s) + m;
}

__global__ __launch_bounds__(256) void l1b_kernel(const _Float16* __restrict__ x,
                                                  const v4i* __restrict__ ptrs,
                                                  const _Float16* __restrict__ LA,
                                                  _Float16* __restrict__ y,
                                                  int n, int h, int half) {
    int t = blockIdx.x * blockDim.x + threadIdx.x;
    if (t >= h) return;
    int i0 = t, i1 = t + h, i2 = t + 2 * h, i3 = t + 3 * h;
    int c1 = i1 < n ? i1 : 0, c2 = i2 < n ? i2 : 0, c3 = i3 < n ? i3 : 0;
    v4i p0 = __builtin_nontemporal_load(ptrs + i0);
    v4i p1 = __builtin_nontemporal_load(ptrs + c1);
    v4i p2 = __builtin_nontemporal_load(ptrs + c2);
    v4i p3 = __builtin_nontemporal_load(ptrs + c3);
    float la0 = (float)__builtin_nontemporal_load(LA + i0);
    float la1 = (float)__builtin_nontemporal_load(LA + c1);
    float la2 = (float)__builtin_nontemporal_load(LA + c2);
    float la3 = (float)__builtin_nontemporal_load(LA + c3);
    float a0 = NEG_INF, b0 = NEG_INF, e0 = NEG_INF, d0 = NEG_INF;
    float a1 = NEG_INF, b1 = NEG_INF, e1 = NEG_INF, d1 = NEG_INF;
    float a2 = NEG_INF, b2 = NEG_INF, e2 = NEG_INF, d2 = NEG_INF;
    float a3 = NEG_INF, b3 = NEG_INF, e3 = NEG_INF, d3 = NEG_INF;
    if (p0.x >= half) a0 = (float)x[p0.x];
    if (p0.y >= half) b0 = (float)x[p0.y];
    if (p0.z >= half) e0 = (float)x[p0.z];
    if (p0.w >= half) d0 = (float)x[p0.w];
    if (p1.x >= half) a1 = (float)x[p1.x];
    if (p1.y >= half) b1 = (float)x[p1.y];
    if (p1.z >= half) e1 = (float)x[p1.z];
    if (p1.w >= half) d1 = (float)x[p1.w];
    if (p2.x >= half) a2 = (float)x[p2.x];
    if (p2.y >= half) b2 = (float)x[p2.y];
    if (p2.z >= half) e2 = (float)x[p2.z];
    if (p2.w >= half) d2 = (float)x[p2.w];
    if (p3.x >= half) a3 = (float)x[p3.x];
    if (p3.y >= half) b3 = (float)x[p3.y];
    if (p3.z >= half) e3 = (float)x[p3.z];
    if (p3.w >= half) d3 = (float)x[p3.w];
    float s0 = merge_lse(la0, plse4(a0, b0, e0, d0));
    float s1 = merge_lse(la1, plse4(a1, b1, e1, d1));
    float s2 = merge_lse(la2, plse4(a2, b2, e2, d2));
    float s3 = merge_lse(la3, plse4(a3, b3, e3, d3));
    __builtin_nontemporal_store((_Float16)s0, y + i0);
    if (i1 < n) __builtin_nontemporal_store((_Float16)s1, y + i1);
    if (i2 < n) __builtin_nontemporal_store((_Float16)s2, y + i2);
    if (i3 < n) __builtin_nontemporal_store((_Float16)s3, y + i3);
}

// Product node: fp16 gather -> fp16 out, 4 nodes/thread, straight-line.
__global__ __launch_bounds__(256) void sum4_h2h_kernel(const _Float16* __restrict__ x,
                                                       const v4i* __restrict__ ptrs,
                                                       _Float16* __restrict__ y, int n, int h) {
    int t = blockIdx.x * blockDim.x + threadIdx.x;
    if (t >= h) return;
    int i0 = t, i1 = t + h, i2 = t + 2 * h, i3 = t + 3 * h;
    int c1 = i1 < n ? i1 : 0, c2 = i2 < n ? i2 : 0, c3 = i3 < n ? i3 : 0;
    v4i p0 = __builtin_nontemporal_load(ptrs + i0);
    v4i p1 = __builtin_nontemporal_load(ptrs + c1);
    v4i p2 = __builtin_nontemporal_load(ptrs + c2);
    v4i p3 = __builtin_nontemporal_load(ptrs + c3);
    float s0 = ((float)x[p0.x] + (float)x[p0.y]) + ((float)x[p0.z] + (float)x[p0.w]);
    float s1 = ((float)x[p1.x] + (float)x[p1.y]) + ((float)x[p1.z] + (float)x[p1.w]);
    float s2 = ((float)x[p2.x] + (float)x[p2.y]) + ((float)x[p2.z] + (float)x[p2.w]);
    float s3 = ((float)x[p3.x] + (float)x[p3.y]) + ((float)x[p3.z] + (float)x[p3.w]);
    __builtin_nontemporal_store((_Float16)s0, y + i0);
    if (i1 < n) __builtin_nontemporal_store((_Float16)s1, y + i1);
    if (i2 < n) __builtin_nontemporal_store((_Float16)s2, y + i2);
    if (i3 < n) __builtin_nontemporal_store((_Float16)s3, y + i3);
}

__device__ __forceinline__ float lse4(float a, float b, float c, float d) {
    float m = fmaxf(fmaxf(a, b), fmaxf(c, d));
    if (m == NEG_INF) return NEG_INF;
    float s = __expf(a - m) + __expf(b - m) + __expf(c - m) + __expf(d - m) + 1e-15f;
    return __logf(s) + m;
}

// Final sum node: fp16 gather -> fp32 out, 4 nodes/thread, straight-line.
__global__ __launch_bounds__(256) void logsum4_h2f_kernel(const _Float16* __restrict__ x,
                                                          const v4i* __restrict__ ptrs,
                                                          float* __restrict__ y, int n, int h) {
    int t = blockIdx.x * blockDim.x + threadIdx.x;
    if (t >= h) return;
    int i0 = t, i1 = t + h, i2 = t + 2 * h, i3 = t + 3 * h;
    int c1 = i1 < n ? i1 : 0, c2 = i2 < n ? i2 : 0, c3 = i3 < n ? i3 : 0;
    v4i p0 = __builtin_nontemporal_load(ptrs + i0);
    v4i p1 = __builtin_nontemporal_load(ptrs + c1);
    v4i p2 = __builtin_nontemporal_load(ptrs + c2);
    v4i p3 = __builtin_nontemporal_load(ptrs + c3);
    float a0 = (float)x[p0.x], b0 = (float)x[p0.y], e0 = (float)x[p0.z], d0 = (float)x[p0.w];
    float a1 = (float)x[p1.x], b1 = (float)x[p1.y], e1 = (float)x[p1.z], d1 = (float)x[p1.w];
    float a2 = (float)x[p2.x], b2 = (float)x[p2.y], e2 = (float)x[p2.z], d2 = (float)x[p2.w];
    float a3 = (float)x[p3.x], b3 = (float)x[p3.y], e3 = (float)x[p3.z], d3 = (float)x[p3.w];
    float s0 = lse4(a0, b0, e0, d0);
    float s1 = lse4(a1, b1, e1, d1);
    float s2 = lse4(a2, b2, e2, d2);
    float s3 = lse4(a3, b3, e3, d3);
    __builtin_nontemporal_store(s0, y + i0);
    if (i1 < n) __builtin_nontemporal_store(s1, y + i1);
    if (i2 < n) __builtin_nontemporal_store(s2, y + i2);
    if (i3 < n) __builtin_nontemporal_store(s3, y + i3);
}

extern "C" void kernel_launch(void* const* d_in, const int* in_sizes, int n_in,
                              void* d_out, int out_size, void* d_ws, size_t ws_size,
                              hipStream_t stream) {
    // d_in dict order: weights, ptrs0, csr0, n0, ptrs1, csr1, n1, ptrs2, csr2, n2, ptrs3, csr3, n3
    const float* w     = (const float*)d_in[0];
    const v4i*   ptrs0 = (const v4i*)d_in[1];
    const v4i*   ptrs1 = (const v4i*)d_in[4];
    const v4i*   ptrs2 = (const v4i*)d_in[7];
    const v4i*   ptrs3 = (const v4i*)d_in[10];

    const int n_vars = in_sizes[0];
    const int n0 = in_sizes[1] / 4;
    const int n1 = in_sizes[4] / 4;
    const int n2 = in_sizes[7] / 4;
    const int n3 = in_sizes[10] / 4;

    // workspace layout (256B-aligned), intermediates fp16
    char* ws = (char*)d_ws;
    size_t off = 0;
    _Float16* wh = (_Float16*)(ws + off); off += ((size_t)n_vars * 2 + 255) & ~(size_t)255;
    _Float16* y0 = (_Float16*)(ws + off); off += ((size_t)n0 * 2 + 255) & ~(size_t)255;
    _Float16* y1 = (_Float16*)(ws + off); off += ((size_t)n1 * 2 + 255) & ~(size_t)255;
    _Float16* y2 = (_Float16*)(ws + off); off += ((size_t)n2 * 2 + 255) & ~(size_t)255;
    _Float16* LA = (_Float16*)(ws + off);
    float* out = (float*)d_out;

    const int B = 256;
    int hc = (n_vars + 3) / 4;
    int h0 = (n0 + 3) / 4, h1 = (n1 + 3) / 4, h2 = (n2 + 3) / 4, h3 = (n3 + 3) / 4;
    int half0 = n0 / 2;   // 4 MB fp16 boundary of y0

    cvt_kernel        <<<(hc + B - 1) / B, B, 0, stream>>>(w, wh, n_vars);
    sum4_enc_kernel   <<<(h0 + B - 1) / B, B, 0, stream>>>(wh, ptrs0, y0, n0, h0);
    l1a_kernel        <<<(h1 + B - 1) / B, B, 0, stream>>>(y0, ptrs1, LA, n1, h1, half0);
    l1b_kernel        <<<(h1 + B - 1) / B, B, 0, stream>>>(y0, ptrs1, LA, y1, n1, h1, half0);
    sum4_h2h_kernel   <<<(h2 + B - 1) / B, B, 0, stream>>>(y1, ptrs2, y2, n2, h2);
    logsum4_h2f_kernel<<<(h3 + B - 1) / B, B, 0, stream>>>(y2, ptrs3, out, n3, h3);
}

// Round 9
// 355.774 us; speedup vs baseline: 2.4961x; 1.0035x over previous
//
#include <hip/hip_runtime.h>
#include <math.h>

#define NEG_INF (-INFINITY)

typedef int      v4i __attribute__((ext_vector_type(4)));
typedef float    v4f __attribute__((ext_vector_type(4)));
typedef _Float16 v4h __attribute__((ext_vector_type(4)));

// fast log1mexp for v < 0: log(1 - e^v). Rel err ~1e-6.
__device__ __forceinline__ float fast_log1mexp(float v) {
    if (v > -0.125f) {
        float e = v * (1.0f + v * (0.5f + v * (0.16666667f + v * 0.041666667f)));
        return __logf(-e);
    }
    return __logf(1.0f - __expf(v));
}

// w (fp32) -> wh (fp16)
__global__ __launch_bounds__(256) void cvt_kernel(const float* __restrict__ w,
                                                  _Float16* __restrict__ wh, int n) {
    int i = blockIdx.x * blockDim.x + threadIdx.x;
    int n4 = n >> 2;
    if (i < n4) {
        v4f v = reinterpret_cast<const v4f*>(w)[i];
        v4h o;
        o.x = (_Float16)v.x; o.y = (_Float16)v.y;
        o.z = (_Float16)v.z; o.w = (_Float16)v.w;
        reinterpret_cast<v4h*>(wh)[i] = o;
    }
    int base = n4 << 2;
    if (i < (n - base)) wh[base + i] = (_Float16)w[base + i];
}

// encoded-x ptr -> clamped index into wh
__device__ __forceinline__ int widx(int p) { int j = (p >> 1) - 1; return j < 0 ? 0 : j; }
// fixup a raw gathered weight per ptr parity/constants
__device__ __forceinline__ float fixw(int p, float v) {
    float r = (p & 1) ? fast_log1mexp(v) : v;
    if (p < 2) r = (p == 0) ? NEG_INF : 0.0f;
    return r;
}

// Layer 0: product node fused with encode. 4 nodes/thread, straight-line.
// (enc is at its request-rate plateau — shape frozen since round 6)
__global__ __launch_bounds__(256) void sum4_enc_kernel(const _Float16* __restrict__ wh,
                                                       const v4i* __restrict__ ptrs,
                                                       _Float16* __restrict__ y, int n, int h) {
    int t = blockIdx.x * blockDim.x + threadIdx.x;
    if (t >= h) return;
    int i0 = t, i1 = t + h, i2 = t + 2 * h, i3 = t + 3 * h;
    int c1 = i1 < n ? i1 : 0, c2 = i2 < n ? i2 : 0, c3 = i3 < n ? i3 : 0;
    v4i p0 = __builtin_nontemporal_load(ptrs + i0);
    v4i p1 = __builtin_nontemporal_load(ptrs + c1);
    v4i p2 = __builtin_nontemporal_load(ptrs + c2);
    v4i p3 = __builtin_nontemporal_load(ptrs + c3);
    float g00 = (float)wh[widx(p0.x)], g01 = (float)wh[widx(p0.y)];
    float g02 = (float)wh[widx(p0.z)], g03 = (float)wh[widx(p0.w)];
    float g10 = (float)wh[widx(p1.x)], g11 = (float)wh[widx(p1.y)];
    float g12 = (float)wh[widx(p1.z)], g13 = (float)wh[widx(p1.w)];
    float g20 = (float)wh[widx(p2.x)], g21 = (float)wh[widx(p2.y)];
    float g22 = (float)wh[widx(p2.z)], g23 = (float)wh[widx(p2.w)];
    float g30 = (float)wh[widx(p3.x)], g31 = (float)wh[widx(p3.y)];
    float g32 = (float)wh[widx(p3.z)], g33 = (float)wh[widx(p3.w)];
    float s0 = (fixw(p0.x, g00) + fixw(p0.y, g01)) + (fixw(p0.z, g02) + fixw(p0.w, g03));
    float s1 = (fixw(p1.x, g10) + fixw(p1.y, g11)) + (fixw(p1.z, g12) + fixw(p1.w, g13));
    float s2 = (fixw(p2.x, g20) + fixw(p2.y, g21)) + (fixw(p2.z, g22) + fixw(p2.w, g23));
    float s3 = (fixw(p3.x, g30) + fixw(p3.y, g31)) + (fixw(p3.z, g32) + fixw(p3.w, g33));
    __builtin_nontemporal_store((_Float16)s0, y + i0);
    if (i1 < n) __builtin_nontemporal_store((_Float16)s1, y + i1);
    if (i2 < n) __builtin_nontemporal_store((_Float16)s2, y + i2);
    if (i3 < n) __builtin_nontemporal_store((_Float16)s3, y + i3);
}

// partial stable LSE (no epsilon): -inf if all inputs -inf.
__device__ __forceinline__ float plse4(float a, float b, float c, float d) {
    float m = fmaxf(fmaxf(a, b), fmaxf(c, d));
    if (m == NEG_INF) return NEG_INF;
    float s = __expf(a - m) + __expf(b - m) + __expf(c - m) + __expf(d - m);
    return __logf(s) + m;
}

// Layer 1 pass A: predicated gathers from the L2-resident lower half of y0.
// 2 nodes/thread -> 1M threads for occupancy.
__global__ __launch_bounds__(256) void l1a_kernel(const _Float16* __restrict__ x,
                                                  const v4i* __restrict__ ptrs,
                                                  _Float16* __restrict__ LA,
                                                  int n, int h, int half) {
    int t = blockIdx.x * blockDim.x + threadIdx.x;
    if (t >= h) return;
    int i0 = t, i1 = t + h;
    int c1 = i1 < n ? i1 : 0;
    v4i p0 = __builtin_nontemporal_load(ptrs + i0);
    v4i p1 = __builtin_nontemporal_load(ptrs + c1);
    float a0 = NEG_INF, b0 = NEG_INF, e0 = NEG_INF, d0 = NEG_INF;
    float a1 = NEG_INF, b1 = NEG_INF, e1 = NEG_INF, d1 = NEG_INF;
    if (p0.x < half) a0 = (float)x[p0.x];
    if (p0.y < half) b0 = (float)x[p0.y];
    if (p0.z < half) e0 = (float)x[p0.z];
    if (p0.w < half) d0 = (float)x[p0.w];
    if (p1.x < half) a1 = (float)x[p1.x];
    if (p1.y < half) b1 = (float)x[p1.y];
    if (p1.z < half) e1 = (float)x[p1.z];
    if (p1.w < half) d1 = (float)x[p1.w];
    float s0 = plse4(a0, b0, e0, d0);
    float s1 = plse4(a1, b1, e1, d1);
    __builtin_nontemporal_store((_Float16)s0, LA + i0);
    if (i1 < n) __builtin_nontemporal_store((_Float16)s1, LA + i1);
}

// exact two-way LSE merge (epsilon once, matching ref)
__device__ __forceinline__ float merge_lse(float LA, float LB) {
    float m = fmaxf(LA, LB);
    if (m == NEG_INF) return NEG_INF;
    float s = __expf(LA - m) + __expf(LB - m) + 1e-15f;
    return __logf(s) + m;
}

// Layer 1 pass B: upper-half gathers + merge. 2 nodes/thread.
__global__ __launch_bounds__(256) void l1b_kernel(const _Float16* __restrict__ x,
                                                  const v4i* __restrict__ ptrs,
                                                  const _Float16* __restrict__ LA,
                                                  _Float16* __restrict__ y,
                                                  int n, int h, int half) {
    int t = blockIdx.x * blockDim.x + threadIdx.x;
    if (t >= h) return;
    int i0 = t, i1 = t + h;
    int c1 = i1 < n ? i1 : 0;
    v4i p0 = __builtin_nontemporal_load(ptrs + i0);
    v4i p1 = __builtin_nontemporal_load(ptrs + c1);
    float la0 = (float)__builtin_nontemporal_load(LA + i0);
    float la1 = (float)__builtin_nontemporal_load(LA + c1);
    float a0 = NEG_INF, b0 = NEG_INF, e0 = NEG_INF, d0 = NEG_INF;
    float a1 = NEG_INF, b1 = NEG_INF, e1 = NEG_INF, d1 = NEG_INF;
    if (p0.x >= half) a0 = (float)x[p0.x];
    if (p0.y >= half) b0 = (float)x[p0.y];
    if (p0.z >= half) e0 = (float)x[p0.z];
    if (p0.w >= half) d0 = (float)x[p0.w];
    if (p1.x >= half) a1 = (float)x[p1.x];
    if (p1.y >= half) b1 = (float)x[p1.y];
    if (p1.z >= half) e1 = (float)x[p1.z];
    if (p1.w >= half) d1 = (float)x[p1.w];
    float s0 = merge_lse(la0, plse4(a0, b0, e0, d0));
    float s1 = merge_lse(la1, plse4(a1, b1, e1, d1));
    __builtin_nontemporal_store((_Float16)s0, y + i0);
    if (i1 < n) __builtin_nontemporal_store((_Float16)s1, y + i1);
}

// Product node (layer 2): 2 nodes/thread -> 500K threads.
__global__ __launch_bounds__(256) void sum4_h2h_kernel(const _Float16* __restrict__ x,
                                                       const v4i* __restrict__ ptrs,
                                                       _Float16* __restrict__ y, int n, int h) {
    int t = blockIdx.x * blockDim.x + threadIdx.x;
    if (t >= h) return;
    int i0 = t, i1 = t + h;
    int c1 = i1 < n ? i1 : 0;
    v4i p0 = __builtin_nontemporal_load(ptrs + i0);
    v4i p1 = __builtin_nontemporal_load(ptrs + c1);
    float s0 = ((float)x[p0.x] + (float)x[p0.y]) + ((float)x[p0.z] + (float)x[p0.w]);
    float s1 = ((float)x[p1.x] + (float)x[p1.y]) + ((float)x[p1.z] + (float)x[p1.w]);
    __builtin_nontemporal_store((_Float16)s0, y + i0);
    if (i1 < n) __builtin_nontemporal_store((_Float16)s1, y + i1);
}

__device__ __forceinline__ float lse4(float a, float b, float c, float d) {
    float m = fmaxf(fmaxf(a, b), fmaxf(c, d));
    if (m == NEG_INF) return NEG_INF;
    float s = __expf(a - m) + __expf(b - m) + __expf(c - m) + __expf(d - m) + 1e-15f;
    return __logf(s) + m;
}

// Final sum node (layer 3): 1 node/thread -> 500K threads.
__global__ __launch_bounds__(256) void logsum4_h2f_kernel(const _Float16* __restrict__ x,
                                                          const v4i* __restrict__ ptrs,
                                                          float* __restrict__ y, int n) {
    int t = blockIdx.x * blockDim.x + threadIdx.x;
    if (t >= n) return;
    v4i p = __builtin_nontemporal_load(ptrs + t);
    float r = lse4((float)x[p.x], (float)x[p.y], (float)x[p.z], (float)x[p.w]);
    __builtin_nontemporal_store(r, y + t);
}

extern "C" void kernel_launch(void* const* d_in, const int* in_sizes, int n_in,
                              void* d_out, int out_size, void* d_ws, size_t ws_size,
                              hipStream_t stream) {
    // d_in dict order: weights, ptrs0, csr0, n0, ptrs1, csr1, n1, ptrs2, csr2, n2, ptrs3, csr3, n3
    const float* w     = (const float*)d_in[0];
    const v4i*   ptrs0 = (const v4i*)d_in[1];
    const v4i*   ptrs1 = (const v4i*)d_in[4];
    const v4i*   ptrs2 = (const v4i*)d_in[7];
    const v4i*   ptrs3 = (const v4i*)d_in[10];

    const int n_vars = in_sizes[0];
    const int n0 = in_sizes[1] / 4;
    const int n1 = in_sizes[4] / 4;
    const int n2 = in_sizes[7] / 4;
    const int n3 = in_sizes[10] / 4;

    // workspace layout (256B-aligned), intermediates fp16
    char* ws = (char*)d_ws;
    size_t off = 0;
    _Float16* wh = (_Float16*)(ws + off); off += ((size_t)n_vars * 2 + 255) & ~(size_t)255;
    _Float16* y0 = (_Float16*)(ws + off); off += ((size_t)n0 * 2 + 255) & ~(size_t)255;
    _Float16* y1 = (_Float16*)(ws + off); off += ((size_t)n1 * 2 + 255) & ~(size_t)255;
    _Float16* y2 = (_Float16*)(ws + off); off += ((size_t)n2 * 2 + 255) & ~(size_t)255;
    _Float16* LA = (_Float16*)(ws + off);
    float* out = (float*)d_out;

    const int B = 256;
    int hc = (n_vars + 3) / 4;
    int h0 = (n0 + 3) / 4;                 // enc: 4 nodes/thread
    int h1 = (n1 + 1) / 2;                 // l1a/l1b: 2 nodes/thread
    int h2 = (n2 + 1) / 2;                 // l2: 2 nodes/thread
    int half0 = n0 / 2;                    // 4 MB fp16 boundary of y0

    cvt_kernel        <<<(hc + B - 1) / B, B, 0, stream>>>(w, wh, n_vars);
    sum4_enc_kernel   <<<(h0 + B - 1) / B, B, 0, stream>>>(wh, ptrs0, y0, n0, h0);
    l1a_kernel        <<<(h1 + B - 1) / B, B, 0, stream>>>(y0, ptrs1, LA, n1, h1, half0);
    l1b_kernel        <<<(h1 + B - 1) / B, B, 0, stream>>>(y0, ptrs1, LA, y1, n1, h1, half0);
    sum4_h2h_kernel   <<<(h2 + B - 1) / B, B, 0, stream>>>(y1, ptrs2, y2, n2, h2);
    logsum4_h2f_kernel<<<(n3 + B - 1) / B, B, 0, stream>>>(y2, ptrs3, out, n3);
}